// Round 8
// baseline (248.481 us; speedup 1.0000x reference)
//
#include <hip/hip_runtime.h>
#include <hip/hip_bf16.h>
#include <hip/hip_fp16.h>

#define NODES 50000
#define NEDGE 800000
#define NPRED 200000

typedef __attribute__((ext_vector_type(8))) short bf16x8;
typedef __attribute__((ext_vector_type(8))) unsigned short u16x8;
typedef __attribute__((ext_vector_type(4))) float f32x4;

__device__ inline float bf2f(unsigned short u) {
    union { unsigned int i; float f; } v; v.i = ((unsigned int)u) << 16; return v.f;
}
__device__ inline unsigned short f2bf(float f) {
    __hip_bfloat16 b = __float2bfloat16(f);
    return *(unsigned short*)&b;
}

// ---------------------------------------------------------------------------
// rank_perm: fused (a) rank pass: rank[e] = atomicAdd(&cnt[dst[e]],1), and
// (b) weight permutation into MFMA B-fragment order (independent work, extra
// blocks). B frag 16x16x32: lane holds B[k][n], n=lane&15, k=(lane>>4)*8+j.
// ---------------------------------------------------------------------------
#define RANK_BLOCKS 782   // ceil(200000/256)
__global__ __launch_bounds__(256) void rank_perm(const int* __restrict__ dstv, int* __restrict__ cnt,
                                                 int* __restrict__ rank, int E4,
                                                 const float* __restrict__ W1, const float* __restrict__ W2,
                                                 const float* __restrict__ Wa,
                                                 unsigned short* __restrict__ pW1,
                                                 unsigned short* __restrict__ pW2,
                                                 unsigned short* __restrict__ pWa) {
    if (blockIdx.x < RANK_BLOCKS) {
        int i = blockIdx.x * 256 + threadIdx.x;
        if (i < E4) {
            int4 d4 = ((const int4*)dstv)[i];
            int4 r4;
            r4.x = atomicAdd(&cnt[d4.x], 1);
            r4.y = atomicAdd(&cnt[d4.y], 1);
            r4.z = atomicAdd(&cnt[d4.z], 1);
            r4.w = atomicAdd(&cnt[d4.w], 1);
            ((int4*)rank)[i] = r4;
        }
        return;
    }
    int t = (blockIdx.x - RANK_BLOCKS) * 256 + threadIdx.x;   // 0..5119
    if (t >= 5120) return;
    const float* W; unsigned short* P; int N;
    if (t < 2048)      { W = W1; P = pW1; N = 128; }
    else if (t < 3072) { W = W2; P = pW2; N = 64;  t -= 2048; }
    else               { W = Wa; P = pWa; N = 128; t -= 3072; }
    int lane = t & 63;
    int kt = (t >> 6) & 3;
    int nt = t >> 8;
    int n = nt * 16 + (lane & 15);
    int k0 = kt * 32 + (lane >> 4) * 8;
#pragma unroll
    for (int j = 0; j < 8; ++j) P[t * 8 + j] = f2bf(W[(k0 + j) * N + n]);
}

__global__ __launch_bounds__(256) void scan_bsum(const int* __restrict__ cnt, int* __restrict__ bsum, int n) {
    __shared__ int s[256];
    int t = threadIdx.x, b = blockIdx.x;
    int base = b * 1024 + t * 4;
    int sum = 0;
#pragma unroll
    for (int j = 0; j < 4; ++j) { int i = base + j; if (i < n) sum += cnt[i]; }
    s[t] = sum; __syncthreads();
    for (int off = 128; off >= 1; off >>= 1) {
        if (t < off) s[t] += s[t + off];
        __syncthreads();
    }
    if (t == 0) bsum[b] = s[0];
}

__global__ void scan_boff(const int* __restrict__ bsum, int* __restrict__ boff, int nb,
                          int* __restrict__ row_ptr, int n) {
    int t = threadIdx.x;           // 64 threads
    int v = (t < nb) ? bsum[t] : 0;
    int orig = v;
    for (int off = 1; off < 64; off <<= 1) {
        int u = __shfl_up(v, off, 64);
        if (t >= off) v += u;
    }
    boff[t] = v - orig;            // exclusive
    if (t == 63) row_ptr[n] = v;   // total = E
}

// row_ptr + dinv + degree-bucket rank (LDS histogram -> one global atomic/bin)
__global__ __launch_bounds__(256) void scan_write(const int* __restrict__ cnt, const int* __restrict__ boff,
                                                  int* __restrict__ row_ptr, float* __restrict__ dinv,
                                                  int* __restrict__ hist, int* __restrict__ rank2, int n) {
    __shared__ int s[256];
    __shared__ int lh[64], lbase[64];
    int t = threadIdx.x, b = blockIdx.x;
    if (t < 64) lh[t] = 0;
    int base = b * 1024 + t * 4;
    int v[4]; int sum = 0;
#pragma unroll
    for (int j = 0; j < 4; ++j) { int i = base + j; v[j] = (i < n) ? cnt[i] : 0; sum += v[j]; }
    s[t] = sum; __syncthreads();
    for (int off = 1; off < 256; off <<= 1) {
        int u = (t >= off) ? s[t - off] : 0;
        __syncthreads();
        s[t] += u;
        __syncthreads();
    }
    int run = s[t] - sum + boff[b];
    int lr[4], bin[4];
#pragma unroll
    for (int j = 0; j < 4; ++j) {
        int i = base + j;
        if (i < n) {
            row_ptr[i] = run; run += v[j];
            dinv[i] = rsqrtf((float)(v[j] + 1));   // +1 self loop
            bin[j] = v[j] < 63 ? v[j] : 63;
            lr[j] = atomicAdd(&lh[bin[j]], 1);
        }
    }
    __syncthreads();
    if (t < 64) lbase[t] = atomicAdd(&hist[t], lh[t]);
    __syncthreads();
#pragma unroll
    for (int j = 0; j < 4; ++j) {
        int i = base + j;
        if (i < n) rank2[i] = lbase[bin[j]] + lr[j];
    }
}

__global__ void scan_hist(int* __restrict__ hist) {   // 64 threads, in-place exclusive scan
    int t = threadIdx.x;
    int v = hist[t];
    int orig = v;
    for (int off = 1; off < 64; off <<= 1) {
        int u = __shfl_up(v, off, 64);
        if (t >= off) v += u;
    }
    hist[t] = v - orig;
}

__global__ __launch_bounds__(256) void scatter_order(const int* __restrict__ cnt, const int* __restrict__ rank2,
                                                     const int* __restrict__ hist, int* __restrict__ order, int n) {
    int i = blockIdx.x * 256 + threadIdx.x;
    if (i < n) {
        int d = cnt[i] < 63 ? cnt[i] : 63;
        order[hist[d] + rank2[i]] = i;
    }
}

__global__ __launch_bounds__(256) void csr_fill2(const int* __restrict__ ei, const int* __restrict__ rank,
                                                 const int* __restrict__ row_ptr, int* __restrict__ colv, int E4) {
    int i = blockIdx.x * 256 + threadIdx.x;
    if (i < E4) {
        int4 s4 = ((const int4*)ei)[i];
        int4 d4 = ((const int4*)(ei + NEDGE))[i];
        int4 r4 = ((const int4*)rank)[i];
        colv[row_ptr[d4.x] + r4.x] = s4.x;
        colv[row_ptr[d4.y] + r4.y] = s4.y;
        colv[row_ptr[d4.z] + r4.z] = s4.z;
        colv[row_ptr[d4.w] + r4.w] = s4.w;
    }
}

// ---------------------------------------------------------------------------
// MFMA GEMM: H[M, NT*16] (bf16) = X[M,128] @ W (pre-permuted bf16 frags).
// ---------------------------------------------------------------------------
template <int NT, bool AFP32>
__global__ __launch_bounds__(256) void gemm_mfma(const void* __restrict__ Xv,
                                                 const unsigned short* __restrict__ perm,
                                                 unsigned short* __restrict__ H, int M) {
    int w = blockIdx.x * 4 + (threadIdx.x >> 6);
    int m0 = w * 16;
    if (m0 >= M) return;
    int lane = threadIdx.x & 63;
    int m = lane & 15, q = lane >> 4;
    size_t row = (size_t)(m0 + m);
    bf16x8 a[4];
    if (AFP32) {
        const float* X = (const float*)Xv;
#pragma unroll
        for (int kt = 0; kt < 4; ++kt) {
            float4 f0 = *(const float4*)&X[row * 128 + kt * 32 + q * 8];
            float4 f1 = *(const float4*)&X[row * 128 + kt * 32 + q * 8 + 4];
            bf16x8 av;
            av[0] = (short)f2bf(f0.x); av[1] = (short)f2bf(f0.y);
            av[2] = (short)f2bf(f0.z); av[3] = (short)f2bf(f0.w);
            av[4] = (short)f2bf(f1.x); av[5] = (short)f2bf(f1.y);
            av[6] = (short)f2bf(f1.z); av[7] = (short)f2bf(f1.w);
            a[kt] = av;
        }
    } else {
        const unsigned short* X = (const unsigned short*)Xv;
#pragma unroll
        for (int kt = 0; kt < 4; ++kt)
            a[kt] = *(const bf16x8*)&X[row * 128 + kt * 32 + q * 8];
    }
    const int N = NT * 16;
#pragma unroll
    for (int nt = 0; nt < NT; ++nt) {
        f32x4 c = {0.f, 0.f, 0.f, 0.f};
#pragma unroll
        for (int kt = 0; kt < 4; ++kt) {
            bf16x8 b = *(const bf16x8*)(perm + (size_t)((nt * 4 + kt) * 64 + lane) * 8);
            c = __builtin_amdgcn_mfma_f32_16x16x32_bf16(a[kt], b, c, 0, 0, 0);
        }
#pragma unroll
        for (int r = 0; r < 4; ++r)
            H[(size_t)(m0 + q * 4 + r) * N + nt * 16 + m] = f2bf(c[r]);
    }
}

// ---------------------------------------------------------------------------
// Aggregation (bf16 gathers, fp32 accumulate, 8-deep ILP, degree-sorted order):
// out[d] = (sum_{s->d} h[s]*dinv[s] + h[d]*dinv[d]) * dinv[d] + bias
// ---------------------------------------------------------------------------
template <int C, bool RELU>
__global__ __launch_bounds__(256) void agg_bf16(const unsigned short* __restrict__ h,
                                                const int* __restrict__ row_ptr, const int* __restrict__ colv,
                                                const float* __restrict__ dinv, const float* __restrict__ bias,
                                                const int* __restrict__ order,
                                                unsigned short* __restrict__ out) {
    constexpr int TPN = C / 8;          // lanes per node
    constexpr int NPB = 256 / TPN;      // nodes per block
    int g = blockIdx.x * NPB + threadIdx.x / TPN;
    if (g >= NODES) return;
    int d = order[g];                   // degree-sorted -> uniform waves
    int c8 = (threadIdx.x % TPN) * 8;
    float dv = dinv[d];
    float acc[8];
    u16x8 self = *(const u16x8*)&h[(size_t)d * C + c8];
#pragma unroll
    for (int j = 0; j < 8; ++j) acc[j] = bf2f(self[j]) * dv;
    int i = row_ptr[d], end = row_ptr[d + 1];
    for (; i + 7 < end; i += 8) {
        int s[8]; float w[8]; u16x8 r[8];
#pragma unroll
        for (int k = 0; k < 8; ++k) s[k] = colv[i + k];
#pragma unroll
        for (int k = 0; k < 8; ++k) w[k] = dinv[s[k]];
#pragma unroll
        for (int k = 0; k < 8; ++k) r[k] = *(const u16x8*)&h[(size_t)s[k] * C + c8];
#pragma unroll
        for (int k = 0; k < 8; ++k)
#pragma unroll
            for (int j = 0; j < 8; ++j) acc[j] += bf2f(r[k][j]) * w[k];
    }
    for (; i + 3 < end; i += 4) {
        int s[4]; float w[4]; u16x8 r[4];
#pragma unroll
        for (int k = 0; k < 4; ++k) s[k] = colv[i + k];
#pragma unroll
        for (int k = 0; k < 4; ++k) w[k] = dinv[s[k]];
#pragma unroll
        for (int k = 0; k < 4; ++k) r[k] = *(const u16x8*)&h[(size_t)s[k] * C + c8];
#pragma unroll
        for (int k = 0; k < 4; ++k)
#pragma unroll
            for (int j = 0; j < 8; ++j) acc[j] += bf2f(r[k][j]) * w[k];
    }
    for (; i < end; ++i) {
        int s0 = colv[i];
        float w0 = dinv[s0];
        u16x8 r0 = *(const u16x8*)&h[(size_t)s0 * C + c8];
#pragma unroll
        for (int j = 0; j < 8; ++j) acc[j] += bf2f(r0[j]) * w0;
    }
    u16x8 ov;
#pragma unroll
    for (int j = 0; j < 8; ++j) {
        float o = acc[j] * dv + bias[c8 + j];
        if (RELU) o = fmaxf(o, 0.f);
        ov[j] = f2bf(o);
    }
    *(u16x8*)&out[(size_t)d * C + c8] = ov;
}

// ---------------------------------------------------------------------------
// decode_mfma4: pred[e] = relu(concat(z[s],z[d]) @ Wa + ba) @ Wb + bb
// B-frags in LDS (lgkmcnt) so the vmcnt queue holds only A/idx prefetch.
// One wave = 4 groups x 32 edges = 128 edges; idx prefetch +2, A prefetch +1.
// Waves [0,3125) cover groups 0..12499 exactly (pos then neg).
// ---------------------------------------------------------------------------
__global__ __launch_bounds__(256) void decode_mfma4(const unsigned short* __restrict__ zb,
                                                    const int* __restrict__ pos, const int* __restrict__ neg,
                                                    const unsigned short* __restrict__ perm,
                                                    const float* __restrict__ ba, const float* __restrict__ Wb,
                                                    const float* __restrict__ bb, float* __restrict__ out, int P) {
    __shared__ unsigned short sB[2048 * 8];   // 32 KB: pWa in B-fragment order
    int tid = threadIdx.x;
#pragma unroll
    for (int i = tid * 8; i < 2048 * 8; i += 256 * 8)
        *(u16x8*)&sB[i] = *(const u16x8*)&perm[i];
    __syncthreads();

    int w = blockIdx.x * 4 + (tid >> 6);
    if (w >= 3125) return;                    // after barrier; no more syncs
    int lane = tid & 63;
    int m = lane & 15, q = lane >> 4;
    float bav[8], wbv[8];
#pragma unroll
    for (int nt = 0; nt < 8; ++nt) { bav[nt] = ba[nt * 16 + m]; wbv[nt] = Wb[nt * 16 + m]; }
    float bbv = bb[0];
    int g0 = w * 4;

    int idxS[3][2], idxD[3][2], base[3];
    bf16x8 A[2][8];
    auto loadIdx = [&](int it) {
        int slot = it % 3;
        int g = g0 + it;
        int half = (g >= 6250) ? 1 : 0;
        const int* src = half ? neg : pos;
        int e0 = (g - half * 6250) * 32;
        base[slot] = half * P + e0;
        idxS[slot][0] = src[e0 + m];      idxD[slot][0] = src[P + e0 + m];
        idxS[slot][1] = src[e0 + 16 + m]; idxD[slot][1] = src[P + e0 + 16 + m];
    };
    auto loadA = [&](int it) {
        int slot = it % 3, buf = it & 1;
        size_t s0 = (size_t)idxS[slot][0] * 64, d0 = (size_t)idxD[slot][0] * 64;
        size_t s1 = (size_t)idxS[slot][1] * 64, d1 = (size_t)idxD[slot][1] * 64;
        A[buf][0] = *(const bf16x8*)(zb + s0 + q * 8);
        A[buf][1] = *(const bf16x8*)(zb + s0 + 32 + q * 8);
        A[buf][2] = *(const bf16x8*)(zb + d0 + q * 8);
        A[buf][3] = *(const bf16x8*)(zb + d0 + 32 + q * 8);
        A[buf][4] = *(const bf16x8*)(zb + s1 + q * 8);
        A[buf][5] = *(const bf16x8*)(zb + s1 + 32 + q * 8);
        A[buf][6] = *(const bf16x8*)(zb + d1 + q * 8);
        A[buf][7] = *(const bf16x8*)(zb + d1 + 32 + q * 8);
    };

    loadIdx(0); loadIdx(1); loadA(0);
#pragma unroll
    for (int it = 0; it < 4; ++it) {
        if (it + 2 < 4) loadIdx(it + 2);
        if (it + 1 < 4) loadA(it + 1);        // prefetch next group's A (vmcnt only)
        int buf = it & 1;
        float p0[4] = {0.f, 0.f, 0.f, 0.f};
        float p1[4] = {0.f, 0.f, 0.f, 0.f};
#pragma unroll
        for (int nt = 0; nt < 8; ++nt) {
            bf16x8 b0 = *(const bf16x8*)&sB[(size_t)((nt * 4 + 0) * 64 + lane) * 8];
            bf16x8 b1 = *(const bf16x8*)&sB[(size_t)((nt * 4 + 1) * 64 + lane) * 8];
            bf16x8 b2 = *(const bf16x8*)&sB[(size_t)((nt * 4 + 2) * 64 + lane) * 8];
            bf16x8 b3 = *(const bf16x8*)&sB[(size_t)((nt * 4 + 3) * 64 + lane) * 8];
            f32x4 c0a = {0.f, 0.f, 0.f, 0.f}, c0b = {0.f, 0.f, 0.f, 0.f};
            f32x4 c1a = {0.f, 0.f, 0.f, 0.f}, c1b = {0.f, 0.f, 0.f, 0.f};
            c0a = __builtin_amdgcn_mfma_f32_16x16x32_bf16(A[buf][0], b0, c0a, 0, 0, 0);
            c1a = __builtin_amdgcn_mfma_f32_16x16x32_bf16(A[buf][4], b0, c1a, 0, 0, 0);
            c0b = __builtin_amdgcn_mfma_f32_16x16x32_bf16(A[buf][2], b2, c0b, 0, 0, 0);
            c1b = __builtin_amdgcn_mfma_f32_16x16x32_bf16(A[buf][6], b2, c1b, 0, 0, 0);
            c0a = __builtin_amdgcn_mfma_f32_16x16x32_bf16(A[buf][1], b1, c0a, 0, 0, 0);
            c1a = __builtin_amdgcn_mfma_f32_16x16x32_bf16(A[buf][5], b1, c1a, 0, 0, 0);
            c0b = __builtin_amdgcn_mfma_f32_16x16x32_bf16(A[buf][3], b3, c0b, 0, 0, 0);
            c1b = __builtin_amdgcn_mfma_f32_16x16x32_bf16(A[buf][7], b3, c1b, 0, 0, 0);
#pragma unroll
            for (int r = 0; r < 4; ++r) {
                p0[r] += fmaxf(c0a[r] + c0b[r] + bav[nt], 0.f) * wbv[nt];
                p1[r] += fmaxf(c1a[r] + c1b[r] + bav[nt], 0.f) * wbv[nt];
            }
        }
#pragma unroll
        for (int off = 1; off <= 8; off <<= 1) {
#pragma unroll
            for (int r = 0; r < 4; ++r) {
                p0[r] += __shfl_xor(p0[r], off, 64);
                p1[r] += __shfl_xor(p1[r], off, 64);
            }
        }
        if (m == 0) {
            int slot = it % 3;
            float4 st0 = { p0[0] + bbv, p0[1] + bbv, p0[2] + bbv, p0[3] + bbv };
            float4 st1 = { p1[0] + bbv, p1[1] + bbv, p1[2] + bbv, p1[3] + bbv };
            *(float4*)&out[base[slot] + q * 4] = st0;
            *(float4*)&out[base[slot] + 16 + q * 4] = st1;
        }
    }
}

// ---------------------------------------------------------------------------
extern "C" void kernel_launch(void* const* d_in, const int* in_sizes, int n_in,
                              void* d_out, int out_size, void* d_ws, size_t ws_size,
                              hipStream_t stream) {
    const int N = NODES, E = NEDGE, P = NPRED;
    const float* x  = (const float*)d_in[0];
    const int*   ei = (const int*)d_in[1];
    const int*  pos = (const int*)d_in[2];
    const int*  neg = (const int*)d_in[3];
    const float* W1 = (const float*)d_in[4];
    const float* b1 = (const float*)d_in[5];
    const float* W2 = (const float*)d_in[6];
    const float* b2 = (const float*)d_in[7];
    const float* Wa = (const float*)d_in[8];
    const float* ba = (const float*)d_in[9];
    const float* Wb = (const float*)d_in[10];
    const float* bb = (const float*)d_in[11];
    float* out = (float*)d_out;

    char* w = (char*)d_ws;
    auto alloc = [&](size_t bytes) { char* p = w; w += (bytes + 255) & ~(size_t)255; return p; };
    int*   cnt     = (int*)alloc((size_t)(N + 64) * 4);   // cnt[N] + hist[64] (one memset)
    int*   hist    = cnt + N;
    int*   rankb   = (int*)alloc((size_t)E * 4);
    int*   rank2   = (int*)alloc((size_t)N * 4);
    int*   order   = (int*)alloc((size_t)N * 4);
    int*   row_ptr = (int*)alloc((size_t)(N + 1) * 4);
    int*   colv    = (int*)alloc((size_t)E * 4);
    float* dinv    = (float*)alloc((size_t)N * 4);
    int*   bsum    = (int*)alloc(64 * 4);
    int*   boff    = (int*)alloc(64 * 4);
    unsigned short* h1b = (unsigned short*)alloc((size_t)N * 128 * 2);  // 12.8 MB
    unsigned short* z1b = (unsigned short*)alloc((size_t)N * 128 * 2);  // 12.8 MB
    unsigned short* h2b = (unsigned short*)alloc((size_t)N * 64 * 2);   // 6.4 MB
    unsigned short* zb  = (unsigned short*)alloc((size_t)N * 64 * 2);   // 6.4 MB
    unsigned short* pW1 = (unsigned short*)alloc(2048 * 8 * 2);         // 32 KB
    unsigned short* pW2 = (unsigned short*)alloc(1024 * 8 * 2);         // 16 KB
    unsigned short* pWa = (unsigned short*)alloc(2048 * 8 * 2);         // 32 KB

    const int nb = (N + 1023) / 1024;  // 49
    hipMemsetAsync(cnt, 0, (size_t)(N + 64) * 4, stream);
    rank_perm<<<RANK_BLOCKS + 20, 256, 0, stream>>>(ei + E, cnt, rankb, E / 4,
                                                    W1, W2, Wa, pW1, pW2, pWa);
    scan_bsum<<<nb, 256, 0, stream>>>(cnt, bsum, N);
    scan_boff<<<1, 64, 0, stream>>>(bsum, boff, nb, row_ptr, N);
    scan_write<<<nb, 256, 0, stream>>>(cnt, boff, row_ptr, dinv, hist, rank2, N);
    scan_hist<<<1, 64, 0, stream>>>(hist);
    scatter_order<<<(N + 255) / 256, 256, 0, stream>>>(cnt, rank2, hist, order, N);
    csr_fill2<<<(E / 4 + 255) / 256, 256, 0, stream>>>(ei, rankb, row_ptr, colv, E / 4);

    // layer 1: h1 = bf16(x @ W1) ; z1 = bf16(relu(agg(h1) + b1))
    gemm_mfma<8, true><<<782, 256, 0, stream>>>(x, pW1, h1b, N);
    agg_bf16<128, true><<<N / 16, 256, 0, stream>>>(h1b, row_ptr, colv, dinv, b1, order, z1b);

    // layer 2: h2 = bf16(z1 @ W2) ; z = bf16(agg(h2) + b2)
    gemm_mfma<4, false><<<782, 256, 0, stream>>>(z1b, pW2, h2b, N);
    agg_bf16<64, false><<<(N + 31) / 32, 256, 0, stream>>>(h2b, row_ptr, colv, dinv, b2, order, zb);

    // decode: 3125 waves x 4 groups, B-frags in LDS, rolling A/idx prefetch
    decode_mfma4<<<782, 256, 0, stream>>>(zb, pos, neg, pWa, ba, Wb, bb, out, P);
}

// Round 9
// 241.181 us; speedup vs baseline: 1.0303x; 1.0303x over previous
//
#include <hip/hip_runtime.h>
#include <hip/hip_bf16.h>
#include <hip/hip_fp16.h>

#define NODES 50000
#define NEDGE 800000
#define NPRED 200000

typedef __attribute__((ext_vector_type(8))) short bf16x8;
typedef __attribute__((ext_vector_type(8))) unsigned short u16x8;
typedef __attribute__((ext_vector_type(4))) float f32x4;

__device__ inline float bf2f(unsigned short u) {
    union { unsigned int i; float f; } v; v.i = ((unsigned int)u) << 16; return v.f;
}
__device__ inline unsigned short f2bf(float f) {
    __hip_bfloat16 b = __float2bfloat16(f);
    return *(unsigned short*)&b;
}

// ---------------------------------------------------------------------------
// rank_perm: fused (a) rank pass: rank[e] = atomicAdd(&cnt[dst[e]],1), and
// (b) weight permutation into MFMA B-fragment order (independent work, extra
// blocks). B frag 16x16x32: lane holds B[k][n], n=lane&15, k=(lane>>4)*8+j.
// ---------------------------------------------------------------------------
#define RANK_BLOCKS 782   // ceil((800000/4)/256)
__global__ __launch_bounds__(256) void rank_perm(const int* __restrict__ dstv, int* __restrict__ cnt,
                                                 int* __restrict__ rank, int E4,
                                                 const float* __restrict__ W1, const float* __restrict__ W2,
                                                 const float* __restrict__ Wa,
                                                 unsigned short* __restrict__ pW1,
                                                 unsigned short* __restrict__ pW2,
                                                 unsigned short* __restrict__ pWa) {
    if (blockIdx.x < RANK_BLOCKS) {
        int i = blockIdx.x * 256 + threadIdx.x;
        if (i < E4) {
            int4 d4 = ((const int4*)dstv)[i];
            int4 r4;
            r4.x = atomicAdd(&cnt[d4.x], 1);
            r4.y = atomicAdd(&cnt[d4.y], 1);
            r4.z = atomicAdd(&cnt[d4.z], 1);
            r4.w = atomicAdd(&cnt[d4.w], 1);
            ((int4*)rank)[i] = r4;
        }
        return;
    }
    int t = (blockIdx.x - RANK_BLOCKS) * 256 + threadIdx.x;   // 0..5119
    if (t >= 5120) return;
    const float* W; unsigned short* P; int N;
    if (t < 2048)      { W = W1; P = pW1; N = 128; }
    else if (t < 3072) { W = W2; P = pW2; N = 64;  t -= 2048; }
    else               { W = Wa; P = pWa; N = 128; t -= 3072; }
    int lane = t & 63;
    int kt = (t >> 6) & 3;
    int nt = t >> 8;
    int n = nt * 16 + (lane & 15);
    int k0 = kt * 32 + (lane >> 4) * 8;
#pragma unroll
    for (int j = 0; j < 8; ++j) P[t * 8 + j] = f2bf(W[(k0 + j) * N + n]);
}

// per-block (1024 elems) sums of cnt (in-degree)
__global__ __launch_bounds__(256) void scan_bsum(const int* __restrict__ cnt, int* __restrict__ bsum, int n) {
    __shared__ int s[256];
    int t = threadIdx.x, b = blockIdx.x;
    int base = b * 1024 + t * 4;
    int sum = 0;
#pragma unroll
    for (int j = 0; j < 4; ++j) { int i = base + j; if (i < n) sum += cnt[i]; }
    s[t] = sum; __syncthreads();
    for (int off = 128; off >= 1; off >>= 1) {
        if (t < off) s[t] += s[t + off];
        __syncthreads();
    }
    if (t == 0) bsum[b] = s[0];
}

// scan_write2: computes own block prefix from bsum (64-lane butterfly),
// writes row_ptr + dinv; block 0 writes row_ptr[n] = E.
__global__ __launch_bounds__(256) void scan_write2(const int* __restrict__ cnt, const int* __restrict__ bsum,
                                                   int* __restrict__ row_ptr, float* __restrict__ dinv,
                                                   int n, int nb) {
    __shared__ int s[256];
    __shared__ int sboff;
    int t = threadIdx.x, b = blockIdx.x;
    if (t < 64) {
        int v  = (t < nb) ? bsum[t] : 0;
        int vp = (t < b) ? v : 0;
#pragma unroll
        for (int off = 1; off < 64; off <<= 1) {
            vp += __shfl_xor(vp, off, 64);
            v  += __shfl_xor(v, off, 64);
        }
        if (t == 0) { sboff = vp; if (b == 0) row_ptr[n] = v; }
    }
    int base = b * 1024 + t * 4;
    int v[4]; int sum = 0;
#pragma unroll
    for (int j = 0; j < 4; ++j) { int i = base + j; v[j] = (i < n) ? cnt[i] : 0; sum += v[j]; }
    s[t] = sum; __syncthreads();
    for (int off = 1; off < 256; off <<= 1) {
        int u = (t >= off) ? s[t - off] : 0;
        __syncthreads();
        s[t] += u;
        __syncthreads();
    }
    int run = s[t] - sum + sboff;
#pragma unroll
    for (int j = 0; j < 4; ++j) {
        int i = base + j;
        if (i < n) {
            row_ptr[i] = run; run += v[j];
            dinv[i] = rsqrtf((float)(v[j] + 1));   // +1 self loop
        }
    }
}

// ---------------------------------------------------------------------------
// fill_gemm1: fused csr_fill (no atomics; rank-slot placement) + layer-1 MFMA
// GEMM h1 = bf16(x @ W1). Blocks [0,FILL_BLOCKS) fill, rest gemm.
// ---------------------------------------------------------------------------
#define FILL_BLOCKS 782
__global__ __launch_bounds__(256) void fill_gemm1(const int* __restrict__ ei, const int* __restrict__ rank,
                                                  const int* __restrict__ row_ptr, int* __restrict__ colv, int E4,
                                                  const float* __restrict__ X,
                                                  const unsigned short* __restrict__ pW1,
                                                  unsigned short* __restrict__ H, int M) {
    if (blockIdx.x < FILL_BLOCKS) {
        int i = blockIdx.x * 256 + threadIdx.x;
        if (i < E4) {
            int4 s4 = ((const int4*)ei)[i];
            int4 d4 = ((const int4*)(ei + NEDGE))[i];
            int4 r4 = ((const int4*)rank)[i];
            colv[row_ptr[d4.x] + r4.x] = s4.x;
            colv[row_ptr[d4.y] + r4.y] = s4.y;
            colv[row_ptr[d4.z] + r4.z] = s4.z;
            colv[row_ptr[d4.w] + r4.w] = s4.w;
        }
        return;
    }
    int w = (blockIdx.x - FILL_BLOCKS) * 4 + (threadIdx.x >> 6);
    int m0 = w * 16;
    if (m0 >= M) return;
    int lane = threadIdx.x & 63;
    int m = lane & 15, q = lane >> 4;
    size_t row = (size_t)(m0 + m);
    bf16x8 a[4];
#pragma unroll
    for (int kt = 0; kt < 4; ++kt) {
        float4 f0 = *(const float4*)&X[row * 128 + kt * 32 + q * 8];
        float4 f1 = *(const float4*)&X[row * 128 + kt * 32 + q * 8 + 4];
        bf16x8 av;
        av[0] = (short)f2bf(f0.x); av[1] = (short)f2bf(f0.y);
        av[2] = (short)f2bf(f0.z); av[3] = (short)f2bf(f0.w);
        av[4] = (short)f2bf(f1.x); av[5] = (short)f2bf(f1.y);
        av[6] = (short)f2bf(f1.z); av[7] = (short)f2bf(f1.w);
        a[kt] = av;
    }
#pragma unroll
    for (int nt = 0; nt < 8; ++nt) {
        f32x4 c = {0.f, 0.f, 0.f, 0.f};
#pragma unroll
        for (int kt = 0; kt < 4; ++kt) {
            bf16x8 b = *(const bf16x8*)(pW1 + (size_t)((nt * 4 + kt) * 64 + lane) * 8);
            c = __builtin_amdgcn_mfma_f32_16x16x32_bf16(a[kt], b, c, 0, 0, 0);
        }
#pragma unroll
        for (int r = 0; r < 4; ++r)
            H[(size_t)(m0 + q * 4 + r) * 128 + nt * 16 + m] = f2bf(c[r]);
    }
}

// ---------------------------------------------------------------------------
// MFMA GEMM (bf16 in): H[M, NT*16] = X[M,128] @ W (pre-permuted frags).
// ---------------------------------------------------------------------------
template <int NT>
__global__ __launch_bounds__(256) void gemm_mfma(const unsigned short* __restrict__ X,
                                                 const unsigned short* __restrict__ perm,
                                                 unsigned short* __restrict__ H, int M) {
    int w = blockIdx.x * 4 + (threadIdx.x >> 6);
    int m0 = w * 16;
    if (m0 >= M) return;
    int lane = threadIdx.x & 63;
    int m = lane & 15, q = lane >> 4;
    size_t row = (size_t)(m0 + m);
    bf16x8 a[4];
#pragma unroll
    for (int kt = 0; kt < 4; ++kt)
        a[kt] = *(const bf16x8*)&X[row * 128 + kt * 32 + q * 8];
    const int N = NT * 16;
#pragma unroll
    for (int nt = 0; nt < NT; ++nt) {
        f32x4 c = {0.f, 0.f, 0.f, 0.f};
#pragma unroll
        for (int kt = 0; kt < 4; ++kt) {
            bf16x8 b = *(const bf16x8*)(perm + (size_t)((nt * 4 + kt) * 64 + lane) * 8);
            c = __builtin_amdgcn_mfma_f32_16x16x32_bf16(a[kt], b, c, 0, 0, 0);
        }
#pragma unroll
        for (int r = 0; r < 4; ++r)
            H[(size_t)(m0 + q * 4 + r) * N + nt * 16 + m] = f2bf(c[r]);
    }
}

// ---------------------------------------------------------------------------
// Aggregation (bf16 gathers, fp32 accumulate, 8-deep ILP, natural order):
// out[d] = (sum_{s->d} h[s]*dinv[s] + h[d]*dinv[d]) * dinv[d] + bias
// ---------------------------------------------------------------------------
template <int C, bool RELU>
__global__ __launch_bounds__(256) void agg_bf16(const unsigned short* __restrict__ h,
                                                const int* __restrict__ row_ptr, const int* __restrict__ colv,
                                                const float* __restrict__ dinv, const float* __restrict__ bias,
                                                unsigned short* __restrict__ out) {
    constexpr int TPN = C / 8;          // lanes per node
    constexpr int NPB = 256 / TPN;      // nodes per block
    int d = blockIdx.x * NPB + threadIdx.x / TPN;
    if (d >= NODES) return;
    int c8 = (threadIdx.x % TPN) * 8;
    float dv = dinv[d];
    float acc[8];
    u16x8 self = *(const u16x8*)&h[(size_t)d * C + c8];
#pragma unroll
    for (int j = 0; j < 8; ++j) acc[j] = bf2f(self[j]) * dv;
    int i = row_ptr[d], end = row_ptr[d + 1];
    for (; i + 7 < end; i += 8) {
        int s[8]; float w[8]; u16x8 r[8];
#pragma unroll
        for (int k = 0; k < 8; ++k) s[k] = colv[i + k];
#pragma unroll
        for (int k = 0; k < 8; ++k) w[k] = dinv[s[k]];
#pragma unroll
        for (int k = 0; k < 8; ++k) r[k] = *(const u16x8*)&h[(size_t)s[k] * C + c8];
#pragma unroll
        for (int k = 0; k < 8; ++k)
#pragma unroll
            for (int j = 0; j < 8; ++j) acc[j] += bf2f(r[k][j]) * w[k];
    }
    for (; i + 3 < end; i += 4) {
        int s[4]; float w[4]; u16x8 r[4];
#pragma unroll
        for (int k = 0; k < 4; ++k) s[k] = colv[i + k];
#pragma unroll
        for (int k = 0; k < 4; ++k) w[k] = dinv[s[k]];
#pragma unroll
        for (int k = 0; k < 4; ++k) r[k] = *(const u16x8*)&h[(size_t)s[k] * C + c8];
#pragma unroll
        for (int k = 0; k < 4; ++k)
#pragma unroll
            for (int j = 0; j < 8; ++j) acc[j] += bf2f(r[k][j]) * w[k];
    }
    for (; i < end; ++i) {
        int s0 = colv[i];
        float w0 = dinv[s0];
        u16x8 r0 = *(const u16x8*)&h[(size_t)s0 * C + c8];
#pragma unroll
        for (int j = 0; j < 8; ++j) acc[j] += bf2f(r0[j]) * w0;
    }
    u16x8 ov;
#pragma unroll
    for (int j = 0; j < 8; ++j) {
        float o = acc[j] * dv + bias[c8 + j];
        if (RELU) o = fmaxf(o, 0.f);
        ov[j] = f2bf(o);
    }
    *(u16x8*)&out[(size_t)d * C + c8] = ov;
}

// ---------------------------------------------------------------------------
// decode_mfma5: pred[e] = relu(concat(z[s],z[d]) @ Wa + ba) @ Wb + bb
// B-frags in LDS (lgkmcnt) so the vmcnt queue holds only A/idx prefetch.
// One wave = 8 groups x 32 edges = 256 edges; idx prefetch +2, A prefetch +1.
// 1563 waves; tail groups clamp to 12499 (duplicate identical stores, benign).
// ---------------------------------------------------------------------------
__global__ __launch_bounds__(256) void decode_mfma5(const unsigned short* __restrict__ zb,
                                                    const int* __restrict__ pos, const int* __restrict__ neg,
                                                    const unsigned short* __restrict__ perm,
                                                    const float* __restrict__ ba, const float* __restrict__ Wb,
                                                    const float* __restrict__ bb, float* __restrict__ out, int P) {
    __shared__ unsigned short sB[2048 * 8];   // 32 KB: pWa in B-fragment order
    int tid = threadIdx.x;
#pragma unroll
    for (int i = tid * 8; i < 2048 * 8; i += 256 * 8)
        *(u16x8*)&sB[i] = *(const u16x8*)&perm[i];
    __syncthreads();

    int w = blockIdx.x * 4 + (tid >> 6);
    if (w >= 1563) return;                    // after barrier; no more syncs
    int lane = tid & 63;
    int m = lane & 15, q = lane >> 4;
    float bav[8], wbv[8];
#pragma unroll
    for (int nt = 0; nt < 8; ++nt) { bav[nt] = ba[nt * 16 + m]; wbv[nt] = Wb[nt * 16 + m]; }
    float bbv = bb[0];
    int g0 = w * 8;

    int idxS[3][2], idxD[3][2], base[3];
    bf16x8 A[2][8];
    auto loadIdx = [&](int it) {
        int slot = it % 3;
        int g = g0 + it; if (g > 12499) g = 12499;   // tail clamp
        int half = (g >= 6250) ? 1 : 0;
        const int* src = half ? neg : pos;
        int e0 = (g - half * 6250) * 32;
        base[slot] = half * P + e0;
        idxS[slot][0] = src[e0 + m];      idxD[slot][0] = src[P + e0 + m];
        idxS[slot][1] = src[e0 + 16 + m]; idxD[slot][1] = src[P + e0 + 16 + m];
    };
    auto loadA = [&](int it) {
        int slot = it % 3, buf = it & 1;
        size_t s0 = (size_t)idxS[slot][0] * 64, d0 = (size_t)idxD[slot][0] * 64;
        size_t s1 = (size_t)idxS[slot][1] * 64, d1 = (size_t)idxD[slot][1] * 64;
        A[buf][0] = *(const bf16x8*)(zb + s0 + q * 8);
        A[buf][1] = *(const bf16x8*)(zb + s0 + 32 + q * 8);
        A[buf][2] = *(const bf16x8*)(zb + d0 + q * 8);
        A[buf][3] = *(const bf16x8*)(zb + d0 + 32 + q * 8);
        A[buf][4] = *(const bf16x8*)(zb + s1 + q * 8);
        A[buf][5] = *(const bf16x8*)(zb + s1 + 32 + q * 8);
        A[buf][6] = *(const bf16x8*)(zb + d1 + q * 8);
        A[buf][7] = *(const bf16x8*)(zb + d1 + 32 + q * 8);
    };

    loadIdx(0); loadIdx(1); loadA(0);
#pragma unroll
    for (int it = 0; it < 8; ++it) {
        if (it + 2 < 8) loadIdx(it + 2);
        if (it + 1 < 8) loadA(it + 1);        // prefetch next group's A (vmcnt only)
        int buf = it & 1;
        float p0[4] = {0.f, 0.f, 0.f, 0.f};
        float p1[4] = {0.f, 0.f, 0.f, 0.f};
#pragma unroll
        for (int nt = 0; nt < 8; ++nt) {
            bf16x8 b0 = *(const bf16x8*)&sB[(size_t)((nt * 4 + 0) * 64 + lane) * 8];
            bf16x8 b1 = *(const bf16x8*)&sB[(size_t)((nt * 4 + 1) * 64 + lane) * 8];
            bf16x8 b2 = *(const bf16x8*)&sB[(size_t)((nt * 4 + 2) * 64 + lane) * 8];
            bf16x8 b3 = *(const bf16x8*)&sB[(size_t)((nt * 4 + 3) * 64 + lane) * 8];
            f32x4 c0a = {0.f, 0.f, 0.f, 0.f}, c0b = {0.f, 0.f, 0.f, 0.f};
            f32x4 c1a = {0.f, 0.f, 0.f, 0.f}, c1b = {0.f, 0.f, 0.f, 0.f};
            c0a = __builtin_amdgcn_mfma_f32_16x16x32_bf16(A[buf][0], b0, c0a, 0, 0, 0);
            c1a = __builtin_amdgcn_mfma_f32_16x16x32_bf16(A[buf][4], b0, c1a, 0, 0, 0);
            c0b = __builtin_amdgcn_mfma_f32_16x16x32_bf16(A[buf][2], b2, c0b, 0, 0, 0);
            c1b = __builtin_amdgcn_mfma_f32_16x16x32_bf16(A[buf][6], b2, c1b, 0, 0, 0);
            c0a = __builtin_amdgcn_mfma_f32_16x16x32_bf16(A[buf][1], b1, c0a, 0, 0, 0);
            c1a = __builtin_amdgcn_mfma_f32_16x16x32_bf16(A[buf][5], b1, c1a, 0, 0, 0);
            c0b = __builtin_amdgcn_mfma_f32_16x16x32_bf16(A[buf][3], b3, c0b, 0, 0, 0);
            c1b = __builtin_amdgcn_mfma_f32_16x16x32_bf16(A[buf][7], b3, c1b, 0, 0, 0);
#pragma unroll
            for (int r = 0; r < 4; ++r) {
                p0[r] += fmaxf(c0a[r] + c0b[r] + bav[nt], 0.f) * wbv[nt];
                p1[r] += fmaxf(c1a[r] + c1b[r] + bav[nt], 0.f) * wbv[nt];
            }
        }
#pragma unroll
        for (int off = 1; off <= 8; off <<= 1) {
#pragma unroll
            for (int r = 0; r < 4; ++r) {
                p0[r] += __shfl_xor(p0[r], off, 64);
                p1[r] += __shfl_xor(p1[r], off, 64);
            }
        }
        if (m == 0) {
            int slot = it % 3;
            float4 st0 = { p0[0] + bbv, p0[1] + bbv, p0[2] + bbv, p0[3] + bbv };
            float4 st1 = { p1[0] + bbv, p1[1] + bbv, p1[2] + bbv, p1[3] + bbv };
            *(float4*)&out[base[slot] + q * 4] = st0;
            *(float4*)&out[base[slot] + 16 + q * 4] = st1;
        }
    }
}

// ---------------------------------------------------------------------------
extern "C" void kernel_launch(void* const* d_in, const int* in_sizes, int n_in,
                              void* d_out, int out_size, void* d_ws, size_t ws_size,
                              hipStream_t stream) {
    const int N = NODES, E = NEDGE, P = NPRED;
    const float* x  = (const float*)d_in[0];
    const int*   ei = (const int*)d_in[1];
    const int*  pos = (const int*)d_in[2];
    const int*  neg = (const int*)d_in[3];
    const float* W1 = (const float*)d_in[4];
    const float* b1 = (const float*)d_in[5];
    const float* W2 = (const float*)d_in[6];
    const float* b2 = (const float*)d_in[7];
    const float* Wa = (const float*)d_in[8];
    const float* ba = (const float*)d_in[9];
    const float* Wb = (const float*)d_in[10];
    const float* bb = (const float*)d_in[11];
    float* out = (float*)d_out;

    char* w = (char*)d_ws;
    auto alloc = [&](size_t bytes) { char* p = w; w += (bytes + 255) & ~(size_t)255; return p; };
    int*   cnt     = (int*)alloc((size_t)N * 4);
    int*   rankb   = (int*)alloc((size_t)E * 4);
    int*   row_ptr = (int*)alloc((size_t)(N + 1) * 4);
    int*   colv    = (int*)alloc((size_t)E * 4);
    float* dinv    = (float*)alloc((size_t)N * 4);
    int*   bsum    = (int*)alloc(64 * 4);
    unsigned short* h1b = (unsigned short*)alloc((size_t)N * 128 * 2);  // 12.8 MB
    unsigned short* z1b = (unsigned short*)alloc((size_t)N * 128 * 2);  // 12.8 MB
    unsigned short* h2b = (unsigned short*)alloc((size_t)N * 64 * 2);   // 6.4 MB
    unsigned short* zb  = (unsigned short*)alloc((size_t)N * 64 * 2);   // 6.4 MB
    unsigned short* pW1 = (unsigned short*)alloc(2048 * 8 * 2);         // 32 KB
    unsigned short* pW2 = (unsigned short*)alloc(1024 * 8 * 2);         // 16 KB
    unsigned short* pWa = (unsigned short*)alloc(2048 * 8 * 2);         // 32 KB

    const int nb = (N + 1023) / 1024;  // 49
    hipMemsetAsync(cnt, 0, (size_t)N * 4, stream);
    rank_perm<<<RANK_BLOCKS + 20, 256, 0, stream>>>(ei + E, cnt, rankb, E / 4,
                                                    W1, W2, Wa, pW1, pW2, pWa);
    scan_bsum<<<nb, 256, 0, stream>>>(cnt, bsum, N);
    scan_write2<<<nb, 256, 0, stream>>>(cnt, bsum, row_ptr, dinv, N, nb);

    // fused: CSR fill + layer-1 GEMM h1 = bf16(x @ W1)
    fill_gemm1<<<FILL_BLOCKS + 782, 256, 0, stream>>>(ei, rankb, row_ptr, colv, E / 4,
                                                      x, pW1, h1b, N);

    // layer 1 agg: z1 = bf16(relu(agg(h1) + b1))
    agg_bf16<128, true><<<N / 16, 256, 0, stream>>>(h1b, row_ptr, colv, dinv, b1, z1b);

    // layer 2: h2 = bf16(z1 @ W2) ; z = bf16(agg(h2) + b2)
    gemm_mfma<4><<<782, 256, 0, stream>>>(z1b, pW2, h2b, N);
    agg_bf16<64, false><<<(N + 31) / 32, 256, 0, stream>>>(h2b, row_ptr, colv, dinv, b2, zb);

    // decode: 1563 waves x 8 groups, B-frags in LDS, rolling A/idx prefetch
    decode_mfma5<<<391, 256, 0, stream>>>(zb, pos, neg, pWa, ba, Wb, bb, out, P);
}